// Round 4
// baseline (682.135 us; speedup 1.0000x reference)
//
#include <hip/hip_runtime.h>

#define N_NODES   100000
#define N_EDGES   1600000
#define F_IN      10
#define HD        128
#define N_LAYERS  3
#define N_GRAPHS  256
#define N_CLASSES 25
#define BN_EPS    1e-5f
#define POOL_TILE 64
#define LDS_PITCH 152   // A/B-stage pitch (shorts): 304 B rows, 16B-aligned, 2-way conflict max
#define CPITCH    136   // C-stage pitch (shorts)

#define NBUCK     196   // ceil(100000/512) row buckets (row >> 9)
#define SCAT_TILE 4096  // edges per scatter block
#define BCAP      9216  // padded bucket capacity (mean 8192, sd ~90 -> +11 sigma)
#define BUCK_CAP  16384 // LDS colstage cap per bucket
#define PREPW_BLKS ((N_LAYERS*HD*HD)/256)   // 192
#define PROJ_BLKS 1024

#define AGG_ND    128   // destination nodes per k_agg block
#define AGG_ECAP  4096  // LDS colidx stage capacity (mean 2048, sd ~45 -> +45 sigma)
#define ACC_PITCH 17    // fp32 accumulator row stride (odd -> bank-spread)

// Sliced feature layout for h/hw (the gathered arrays):
//   feature f of node v lives at slice s = f>>4, short offset s*(N*16) + v*16 + (f&15).
//   Each slice = 100000*32 B = 3.2 MB < 4 MB per-XCD L2. k_agg pins slice s to
//   XCD s (blockIdx%8 round-robin) -> gathers are L2-resident (R2: FETCH 187->45MB).
#define SLICE_U4  ((size_t)N_NODES*2)   // uint4 stride per slice
#define SLICE_U1  ((size_t)N_NODES*8)   // unsigned stride per slice

typedef __attribute__((ext_vector_type(8))) short bf8;
typedef __attribute__((ext_vector_type(4))) float f32x4;

static __device__ __forceinline__ unsigned short f2bf(float f){
    unsigned u = __float_as_uint(f);
    unsigned r = (u + 0x7fffu + ((u >> 16) & 1u)) >> 16;
    return (unsigned short)r;
}
static __device__ __forceinline__ float bflo(unsigned u){ return __uint_as_float(u << 16); }
static __device__ __forceinline__ float bfhi(unsigned u){ return __uint_as_float(u & 0xffff0000u); }
static __device__ __forceinline__ unsigned packbf(float a, float b){
    return (unsigned)f2bf(a) | ((unsigned)f2bf(b) << 16);
}

// ---------------- fused scatter + WT transpose + proj (3 blockIdx ranges) ----------------
__global__ __launch_bounds__(256) void k_scatter(const int* __restrict__ rows,
        const int* __restrict__ cols, int* __restrict__ gcur,
        unsigned* __restrict__ ebuf, int e, int nsb,
        const float* __restrict__ Wc, unsigned short* __restrict__ WT,
        const float* __restrict__ x, const float* __restrict__ Wp,
        const float* __restrict__ bp, unsigned* __restrict__ hbf, int n){
    __shared__ int lbase[NBUCK];
    __shared__ int lcur[NBUCK];
    __shared__ int gbase[NBUCK];
    __shared__ int sbuf[256];
    __shared__ unsigned sedge[SCAT_TILE];
    __shared__ unsigned char sbuck[SCAT_TILE];
    __shared__ float sW[F_IN*HD];
    __shared__ float sb[HD];
    int t = threadIdx.x;

    if (blockIdx.x >= nsb){
        int bid2 = blockIdx.x - nsb;
        if (bid2 < PREPW_BLKS){                            // WT transpose
            int i = bid2*256 + t;
            int l = i >> 14;
            int r = (i >> 7) & 127;
            int c = i & 127;
            WT[(l << 14) + c*HD + r] = f2bf(Wc[i]);
            return;
        }
        int bid = bid2 - PREPW_BLKS;                       // proj
        for (int q = t; q < F_IN*HD; q += 256) sW[q] = Wp[q];
        if (t < HD) sb[t] = bp[t];
        __syncthreads();
        int j  = t & 63;
        int ln = t >> 6;
        size_t sbase = (size_t)(j >> 3)*SLICE_U1 + (j & 7);   // sliced output
        for (int n0 = bid*4 + ln; n0 < n; n0 += PROJ_BLKS*4){
            float a0 = sb[2*j], a1 = sb[2*j+1];
            #pragma unroll
            for (int k = 0; k < F_IN; k++){
                float xv = x[(size_t)n0*F_IN + k];
                a0 += xv * sW[k*HD + 2*j];
                a1 += xv * sW[k*HD + 2*j+1];
            }
            hbf[sbase + (size_t)n0*8] = packbf(fmaxf(a0, 0.f), fmaxf(a1, 0.f));
        }
        return;
    }

    // ---- edge scatter range ----
    int i0 = blockIdx.x*SCAT_TILE + t;
    int r[16], c[16];
    if (t < NBUCK) lcur[t] = 0;
    __syncthreads();
    #pragma unroll
    for (int k = 0; k < 16; k++){
        int i = i0 + k*256;
        if (i < e){
            r[k] = rows[i]; c[k] = cols[i];
            atomicAdd(&lcur[r[k] >> 9], 1);
        } else r[k] = -1;
    }
    __syncthreads();
    int myc = (t < NBUCK) ? lcur[t] : 0;
    sbuf[t] = myc;
    __syncthreads();
    for (int d = 1; d < 256; d <<= 1){
        int tv = (t >= d) ? sbuf[t-d] : 0;
        __syncthreads();
        sbuf[t] += tv;
        __syncthreads();
    }
    if (t < NBUCK){
        lbase[t] = sbuf[t] - myc;
        lcur[t]  = sbuf[t] - myc;
        if (myc > 0) gbase[t] = t*BCAP + atomicAdd(&gcur[t], myc);
    }
    __syncthreads();
    #pragma unroll
    for (int k = 0; k < 16; k++){
        if (r[k] >= 0){
            int bk = r[k] >> 9;
            int off = atomicAdd(&lcur[bk], 1);
            sedge[off] = ((unsigned)(r[k] & 511) << 17) | (unsigned)c[k];
            sbuck[off] = (unsigned char)bk;
        }
    }
    __syncthreads();
    int tot = sbuf[255];
    for (int i = t; i < tot; i += 256){
        int bk = sbuck[i];
        ebuf[gbase[bk] + (i - lbase[bk])] = sedge[i];
    }
}

// ---------------- k_build (unchanged) ----------------
__global__ __launch_bounds__(512) void k_build(const unsigned* __restrict__ ebuf,
        const int* __restrict__ gcur, int* __restrict__ rowptr,
        float* __restrict__ dinv, int* __restrict__ colidx, int n, int etot){
    __shared__ int hist[512];
    __shared__ int cur[512];
    __shared__ int colstage[BUCK_CAP];
    __shared__ int sscan[256];
    int t = threadIdx.x;
    int gval = (t < NBUCK) ? gcur[t] : 0;
    if (t < 256) sscan[t] = gval;
    __syncthreads();
    for (int d = 1; d < 256; d <<= 1){
        int tv = (t < 256 && t >= d) ? sscan[t-d] : 0;
        __syncthreads();
        if (t < 256) sscan[t] += tv;
        __syncthreads();
    }
    int b = blockIdx.x;
    int cnt = gcur[b];
    int s   = sscan[b] - cnt;          // dense base in colidx
    int sp  = b*BCAP;                  // padded base in ebuf
    int row0 = b << 9;
    int nrows = min(512, n - row0);
    if (b == 0 && t == 0) rowptr[n] = etot;
    hist[t] = 0;
    __syncthreads();
    for (int i = t; i < cnt; i += 512)
        atomicAdd(&hist[ebuf[sp + i] >> 17], 1);
    __syncthreads();
    int myc = hist[t];
    cur[t] = myc;
    __syncthreads();
    for (int d = 1; d < 512; d <<= 1){
        int tv = (t >= d) ? cur[t-d] : 0;
        __syncthreads();
        cur[t] += tv;
        __syncthreads();
    }
    int excl = cur[t] - myc;
    if (t < nrows){
        rowptr[row0 + t] = s + excl;
        dinv[row0 + t] = rsqrtf((float)(myc + 1));   // +1 self loop
    }
    cur[t] = excl;
    __syncthreads();
    for (int i = t; i < cnt; i += 512){
        unsigned v = ebuf[sp + i];
        int off = atomicAdd(&cur[v >> 17], 1);
        colstage[off] = (int)(v & 0x1ffffu);
    }
    __syncthreads();
    for (int i = t; i < cnt; i += 512)
        colidx[s + i] = colstage[i];
}

// ---------------- layer GEMM (bf16 MFMA): 512 threads, 128-row tile ----------------
// Sliced-layout I/O; LDS layout and MFMA math unchanged -> bit-identical output.
__global__ __launch_bounds__(512) void k_gemm(const uint4* __restrict__ h4,
        const unsigned short* __restrict__ WT, const float* __restrict__ dinv,
        uint4* __restrict__ hw, int n){
    extern __shared__ char smem[];
    unsigned short* As = (unsigned short*)smem;            // 128 x LDS_PITCH
    unsigned short* Bs = As + 128*LDS_PITCH;               // 128 x LDS_PITCH
    int tid = threadIdx.x;
    int row0 = blockIdx.x * 128;

    const uint4* w4 = (const uint4*)WT;
    #pragma unroll
    for (int q = tid; q < 1024; q += 512){                 // A: 128 rows x 8 slices x 32B
        int r = q & 127, sc = q >> 7;
        int grow = row0 + r;
        uint4 v0 = make_uint4(0u,0u,0u,0u), v1 = v0;
        if (grow < n){
            size_t bidx = (size_t)sc*SLICE_U4 + (size_t)grow*2;
            v0 = h4[bidx]; v1 = h4[bidx + 1];
        }
        *(uint4*)&As[r*LDS_PITCH + sc*16]     = v0;
        *(uint4*)&As[r*LDS_PITCH + sc*16 + 8] = v1;
    }
    #pragma unroll
    for (int q = tid; q < 2048; q += 512){                 // B: contiguous WT
        int r = q >> 4, c = q & 15;
        *(uint4*)&Bs[r*LDS_PITCH + c*8] = w4[r*16 + c];
    }
    __syncthreads();

    int w = tid >> 6, lane = tid & 63;                     // 8 waves
    int l15 = lane & 15, quad = lane >> 4;
    f32x4 acc[8];
    #pragma unroll
    for (int ct = 0; ct < 8; ct++) acc[ct] = (f32x4){0.f,0.f,0.f,0.f};

    int arow = w*16 + l15;
    #pragma unroll
    for (int kc = 0; kc < 4; kc++){
        int ko = kc*32 + quad*8;
        bf8 a = *(const bf8*)&As[arow*LDS_PITCH + ko];
        #pragma unroll
        for (int ct = 0; ct < 8; ct++){
            bf8 b = *(const bf8*)&Bs[(ct*16 + l15)*LDS_PITCH + ko];
            acc[ct] = __builtin_amdgcn_mfma_f32_16x16x32_bf16(a, b, acc[ct], 0, 0, 0);
        }
    }
    __syncthreads();                                       // done reading As/Bs

    unsigned short* CS = As;
    #pragma unroll
    for (int reg = 0; reg < 4; reg++){
        int rloc = w*16 + quad*4 + reg;
        int grow = row0 + rloc;
        float dv = (grow < n) ? dinv[grow] : 0.f;
        #pragma unroll
        for (int ct = 0; ct < 8; ct++)
            CS[rloc*CPITCH + ct*16 + l15] = f2bf(acc[ct][reg] * dv);
    }
    __syncthreads();

    #pragma unroll
    for (int q = tid; q < 1024; q += 512){                 // sliced store-out
        int r = q & 127, sc = q >> 7;
        int grow = row0 + r;
        if (grow < n){
            size_t bidx = (size_t)sc*SLICE_U4 + (size_t)grow*2;
            hw[bidx]     = *(const uint4*)&CS[r*CPITCH + sc*16];
            hw[bidx + 1] = *(const uint4*)&CS[r*CPITCH + sc*16 + 8];
        }
    }
}

// ---------------- aggregation + bias + BN + relu (XCD-sliced, edge-parallel) ----------------
// R18: edge-parallel segmented reduction. The three measured shapes all pay
// either max(deg) divergence (R1/R2 node-parallel) or per-node shuffle
// overhead (R3 slot-parallel). Here 128 lane-pairs sweep the block's
// contiguous dst-sorted edge list in equal contiguous runs (perfect balance,
// zero divergence, zero shuffles), accumulate same-dst runs in registers and
// flush to an LDS fp32 accumulator (ds_add_f32) only on dst change (~1 flush
// per mean-deg=17 edges). Concurrent lanes touch dsts ~16 edges apart ->
// distinct atomic addresses; ACC_PITCH=17 spreads banks. Self + BN + store in
// a balanced epilogue. fp32 reorder within node-sum: tolerance already
// validated (R3 passed, absmax bf16-dominated).
__global__ __launch_bounds__(256) void k_agg(const uint4* __restrict__ hw4,
        const int* __restrict__ rowptr, const int* __restrict__ colidx,
        const float* __restrict__ dinv, const float* __restrict__ bc,
        const float* __restrict__ bmean, const float* __restrict__ bvar,
        const float* __restrict__ bgamma, const float* __restrict__ bbeta,
        uint4* __restrict__ houtb, int n){
    __shared__ unsigned scol[AGG_ECAP];        // (dst_local<<17) | src_node
    __shared__ int srp[AGG_ND + 1];
    __shared__ float accum[AGG_ND * ACC_PITCH];
    int tid = threadIdx.x;
    int slice = blockIdx.x & 7;
    int chunk = blockIdx.x >> 3;
    int n0 = chunk * AGG_ND;
    int nloc = min(AGG_ND, n - n0);

    for (int i = tid; i <= nloc; i += 256) srp[i] = rowptr[n0 + i];
    for (int i = tid; i < AGG_ND*ACC_PITCH; i += 256) accum[i] = 0.f;
    __syncthreads();
    int ebase = srp[0];
    int ecnt  = srp[nloc] - ebase;
    bool inl = (ecnt <= AGG_ECAP);
    if (inl){
        for (int i = tid; i < ecnt; i += 256) scol[i] = (unsigned)colidx[ebase + i];
        __syncthreads();
        // owner pass: tag each staged edge with its local dst (exclusive ranges)
        for (int nd = tid; nd < nloc; nd += 256){
            unsigned tag = (unsigned)nd << 17;
            int s = srp[nd] - ebase, e = srp[nd+1] - ebase;
            for (int j = s; j < e; j++) scol[j] += tag;
        }
    }
    __syncthreads();

    const uint4* base = hw4 + (size_t)slice*SLICE_U4;
    int g  = tid >> 1;            // 0..127 edge-group
    int hf = tid & 1;             // 16B half of the 32B row-slice

    auto fetch_pv = [&](int i)->unsigned {
        if (inl) return scol[i];
        int c = colidx[ebase + i];
        int lo = 0, hi = nloc - 1;
        while (lo < hi){ int mid = (lo + hi + 1) >> 1; if (srp[mid] - ebase <= i) lo = mid; else hi = mid - 1; }
        return ((unsigned)lo << 17) | (unsigned)c;
    };

    #define ACC(dst, v) { dst[0]+=bflo(v.x); dst[1]+=bfhi(v.x); \
                          dst[2]+=bflo(v.y); dst[3]+=bfhi(v.y); \
                          dst[4]+=bflo(v.z); dst[5]+=bfhi(v.z); \
                          dst[6]+=bflo(v.w); dst[7]+=bfhi(v.w); }
    #define FLUSH(nd) { float* ap = &accum[(nd)*ACC_PITCH + hf*8]; \
                        _Pragma("unroll") \
                        for (int j = 0; j < 8; j++) atomicAdd(&ap[j], a[j]); }

    int npg = (ecnt + 127) >> 7;
    int i0 = g*npg, i1 = min(i0 + npg, ecnt);
    if (i0 < i1){
        float a[8];
        int cur = -1;
        unsigned pv = fetch_pv(i0);
        uint4 v = base[(size_t)(pv & 0x1ffffu)*2 + hf];
        for (int i = i0; i < i1; i++){
            unsigned pvn = 0u;
            uint4 vn = make_uint4(0u,0u,0u,0u);
            if (i + 1 < i1){
                pvn = fetch_pv(i + 1);
                vn = base[(size_t)(pvn & 0x1ffffu)*2 + hf];   // next gather in flight
            }
            int nd = (int)(pv >> 17);
            if (nd != cur){
                if (cur >= 0) FLUSH(cur);
                cur = nd;
                #pragma unroll
                for (int j = 0; j < 8; j++) a[j] = 0.f;
            }
            ACC(a, v);
            pv = pvn; v = vn;
        }
        FLUSH(cur);
    }
    #undef ACC
    #undef FLUSH
    __syncthreads();

    // epilogue: self + dinv + BN + relu + pack (256 threads = 128 nodes x 2 halves)
    int nd = tid >> 1, ehf = tid & 1;
    if (nd < nloc){
        int node = n0 + nd;
        uint4 self = base[(size_t)node*2 + ehf];
        float sm[8];
        sm[0] = bflo(self.x); sm[1] = bfhi(self.x);
        sm[2] = bflo(self.y); sm[3] = bfhi(self.y);
        sm[4] = bflo(self.z); sm[5] = bfhi(self.z);
        sm[6] = bflo(self.w); sm[7] = bfhi(self.w);
        float dv = dinv[node];
        int f4 = slice*4 + ehf*2;
        float cb[8], cm[8], cv[8], cg[8], cbe[8];
        *(float4*)&cb[0]  = ((const float4*)bc)[f4];     *(float4*)&cb[4]  = ((const float4*)bc)[f4+1];
        *(float4*)&cm[0]  = ((const float4*)bmean)[f4];  *(float4*)&cm[4]  = ((const float4*)bmean)[f4+1];
        *(float4*)&cv[0]  = ((const float4*)bvar)[f4];   *(float4*)&cv[4]  = ((const float4*)bvar)[f4+1];
        *(float4*)&cg[0]  = ((const float4*)bgamma)[f4]; *(float4*)&cg[4]  = ((const float4*)bgamma)[f4+1];
        *(float4*)&cbe[0] = ((const float4*)bbeta)[f4];  *(float4*)&cbe[4] = ((const float4*)bbeta)[f4+1];
        const float* ap = &accum[nd*ACC_PITCH + ehf*8];
        float r[8];
        #pragma unroll
        for (int j = 0; j < 8; j++){
            float sum = ap[j] + sm[j];
            float rx = (sum*dv + cb[j] - cm[j]) * rsqrtf(cv[j] + BN_EPS) * cg[j] + cbe[j];
            r[j] = fmaxf(rx, 0.f);
        }
        uint4 o;
        o.x = packbf(r[0], r[1]);
        o.y = packbf(r[2], r[3]);
        o.z = packbf(r[4], r[5]);
        o.w = packbf(r[6], r[7]);
        houtb[(size_t)slice*SLICE_U4 + (size_t)node*2 + ehf] = o;
    }
}

// ---------------- pooling on bf16 h (fp32 accumulate; sliced input) ----------------
__global__ void k_pool(const unsigned* __restrict__ hb, const int* __restrict__ batch,
        float* __restrict__ gsum, int* __restrict__ gmax, int n){
    int q = threadIdx.x;   // 0..63 feature pair
    int start = blockIdx.x * POOL_TILE;
    int end = min(start + POOL_TILE, n);
    if (start >= end) return;
    size_t sbase = (size_t)(q >> 3)*SLICE_U1 + (q & 7);
    int cur = batch[start];
    float s0 = 0.f, s1 = 0.f, m0 = 0.f, m1 = 0.f;
    for (int i = start; i < end; i++){
        int b = batch[i];
        unsigned v = hb[sbase + (size_t)i*8];
        float v0 = bflo(v), v1 = bfhi(v);
        if (b != cur){
            atomicAdd(&gsum[cur*HD + 2*q],     s0);
            atomicAdd(&gsum[cur*HD + 2*q + 1], s1);
            atomicMax(&gmax[cur*HD + 2*q],     __float_as_int(m0));
            atomicMax(&gmax[cur*HD + 2*q + 1], __float_as_int(m1));
            s0 = s1 = m0 = m1 = 0.f; cur = b;
        }
        s0 += v0; s1 += v1;
        m0 = fmaxf(m0, v0); m1 = fmaxf(m1, v1);
    }
    atomicAdd(&gsum[cur*HD + 2*q],     s0);
    atomicAdd(&gsum[cur*HD + 2*q + 1], s1);
    atomicMax(&gmax[cur*HD + 2*q],     __float_as_int(m0));
    atomicMax(&gmax[cur*HD + 2*q + 1], __float_as_int(m1));
}

// ---------------- fused head: count (binary search) + MLP1 + MLP2 ----------------
__global__ void k_head(const float* __restrict__ gsum, const int* __restrict__ gmax,
        const int* __restrict__ batch, const float* __restrict__ W1,
        const float* __restrict__ b1, const float* __restrict__ W2,
        const float* __restrict__ b2, float* __restrict__ out, int n){
    __shared__ float gv[2*HD];
    __shared__ float hid[HD];
    __shared__ int bound[2];
    int g = blockIdx.x, j = threadIdx.x;   // 128 threads
    if (j < 2){
        int target = g + j;
        int lo = 0, hi = n;
        while (lo < hi){ int mid = (lo + hi) >> 1; if (batch[mid] < target) lo = mid + 1; else hi = mid; }
        bound[j] = lo;
    }
    __syncthreads();
    float denom = (float)max(bound[1] - bound[0], 1);
    gv[j]    = gsum[g*HD+j] / denom;
    gv[HD+j] = __int_as_float(gmax[g*HD+j]);   // 0 for empty graphs (matches guard)
    __syncthreads();
    float acc = b1[j];
    #pragma unroll 8
    for (int k = 0; k < 2*HD; k++) acc += gv[k]*W1[k*HD + j];
    hid[j] = fmaxf(acc, 0.f);
    __syncthreads();
    if (j < N_CLASSES){
        float o = b2[j];
        #pragma unroll 4
        for (int k = 0; k < HD; k++) o += hid[k]*W2[k*N_CLASSES + j];
        out[g*N_CLASSES + j] = o;
    }
}

// ---------------- launch ----------------
extern "C" void kernel_launch(void* const* d_in, const int* in_sizes, int n_in,
                              void* d_out, int out_size, void* d_ws, size_t ws_size,
                              hipStream_t stream){
    const float* x   = (const float*)d_in[0];
    const int*  eidx = (const int*)d_in[1];
    const int* batch = (const int*)d_in[2];
    const float* Wp  = (const float*)d_in[3];
    const float* bp  = (const float*)d_in[4];
    const float* Wc  = (const float*)d_in[5];
    const float* bc  = (const float*)d_in[6];
    const float* bng = (const float*)d_in[7];
    const float* bnb = (const float*)d_in[8];
    const float* bnm = (const float*)d_in[9];
    const float* bnv = (const float*)d_in[10];
    const float* W1  = (const float*)d_in[11];
    const float* b1  = (const float*)d_in[12];
    const float* W2  = (const float*)d_in[13];
    const float* b2  = (const float*)d_in[14];
    float* out = (float*)d_out;

    // workspace (~68 MB). gcur|gsum|gmax contiguous -> one memset.
    char* ws = (char*)d_ws;
    size_t off = 0;
    unsigned short* h_bf  = (unsigned short*)(ws + off); off += (size_t)N_NODES*HD*2;  // 25.6 MB (sliced)
    unsigned short* hw_bf = (unsigned short*)(ws + off); off += (size_t)N_NODES*HD*2;  // 25.6 MB (sliced)
    unsigned short* WT = (unsigned short*)(ws + off); off += (size_t)N_LAYERS*HD*HD*2; // 98 KB
    float* dinv   = (float*)(ws + off); off += (size_t)N_NODES*4;
    int*   rowptr = (int*)  (ws + off); off += (size_t)(N_NODES+16)*4;
    int*   colidx = (int*)  (ws + off); off += (size_t)N_EDGES*4;                      // 6.4 MB
    unsigned* ebuf= (unsigned*)(ws + off); off += (size_t)NBUCK*BCAP*4;                // 7.2 MB padded
    int*   gcur   = (int*)  (ws + off); off += 1024;                                   // zeroed region start
    float* gsum   = (float*)(ws + off); off += (size_t)N_GRAPHS*HD*4;
    int*   gmax   = (int*)  (ws + off); off += (size_t)N_GRAPHS*HD*4;

    const int* rows = eidx;             // targets (aggregation index)
    const int* cols = eidx + N_EDGES;   // sources (gather index)

    // single memset: gcur + gsum + gmax (contiguous)
    hipMemsetAsync(gcur, 0, 1024 + (size_t)(N_GRAPHS*HD*2)*4, stream);

    int nsb = (N_EDGES + SCAT_TILE - 1)/SCAT_TILE;   // 391
    k_scatter<<<nsb + PREPW_BLKS + PROJ_BLKS, 256, 0, stream>>>(rows, cols, gcur, ebuf,
        N_EDGES, nsb, Wc, WT, x, Wp, bp, (unsigned*)h_bf, N_NODES);
    k_build  <<<NBUCK, 512, 0, stream>>>(ebuf, gcur, rowptr, dinv, colidx, N_NODES, N_EDGES);

    int ntiles = (N_NODES + 127)/128;   // 782
    int aggblk = ((N_NODES + AGG_ND - 1)/AGG_ND) * 8;     // 782 chunks x 8 slices
    size_t shmem = (size_t)(2*128*LDS_PITCH)*2;   // 77,824 B -> 2 blocks/CU, 16 waves/CU
    for (int l = 0; l < N_LAYERS; l++){
        k_gemm<<<ntiles, 512, shmem, stream>>>((const uint4*)h_bf, WT + (size_t)l*HD*HD, dinv,
            (uint4*)hw_bf, N_NODES);
        k_agg<<<aggblk, 256, 0, stream>>>((const uint4*)hw_bf, rowptr, colidx, dinv,
            bc + l*HD, bnm + l*HD, bnv + l*HD, bng + l*HD, bnb + l*HD,
            (uint4*)h_bf, N_NODES);
    }

    k_pool<<<(N_NODES+POOL_TILE-1)/POOL_TILE, 64, 0, stream>>>((const unsigned*)h_bf, batch, gsum, gmax, N_NODES);
    k_head<<<N_GRAPHS, 128, 0, stream>>>(gsum, gmax, batch, W1, b1, W2, b2, out, N_NODES);
}

// Round 5
// 405.764 us; speedup vs baseline: 1.6811x; 1.6811x over previous
//
#include <hip/hip_runtime.h>

#define N_NODES   100000
#define N_EDGES   1600000
#define F_IN      10
#define HD        128
#define N_LAYERS  3
#define N_GRAPHS  256
#define N_CLASSES 25
#define BN_EPS    1e-5f
#define POOL_TILE 64
#define LDS_PITCH 152   // A/B-stage pitch (shorts): 304 B rows, 16B-aligned, 2-way conflict max
#define CPITCH    136   // C-stage pitch (shorts)

#define NBUCK     196   // ceil(100000/512) row buckets (row >> 9)
#define SCAT_TILE 4096  // edges per scatter block
#define BCAP      9216  // padded bucket capacity (mean 8192, sd ~90 -> +11 sigma)
#define BUCK_CAP  16384 // LDS colstage cap per bucket
#define PREPW_BLKS ((N_LAYERS*HD*HD)/256)   // 192
#define PROJ_BLKS 1024

typedef __attribute__((ext_vector_type(8))) short bf8;
typedef __attribute__((ext_vector_type(4))) float f32x4;

static __device__ __forceinline__ unsigned short f2bf(float f){
    unsigned u = __float_as_uint(f);
    unsigned r = (u + 0x7fffu + ((u >> 16) & 1u)) >> 16;
    return (unsigned short)r;
}
static __device__ __forceinline__ float bflo(unsigned u){ return __uint_as_float(u << 16); }
static __device__ __forceinline__ float bfhi(unsigned u){ return __uint_as_float(u & 0xffff0000u); }
static __device__ __forceinline__ unsigned packbf(float a, float b){
    return (unsigned)f2bf(a) | ((unsigned)f2bf(b) << 16);
}

// ---------------- fused scatter + WT transpose + proj (3 blockIdx ranges, R13 exact) ----------------
__global__ __launch_bounds__(256) void k_scatter(const int* __restrict__ rows,
        const int* __restrict__ cols, int* __restrict__ gcur,
        unsigned* __restrict__ ebuf, int e, int nsb,
        const float* __restrict__ Wc, unsigned short* __restrict__ WT,
        const float* __restrict__ x, const float* __restrict__ Wp,
        const float* __restrict__ bp, unsigned* __restrict__ hbf, int n){
    __shared__ int lbase[NBUCK];
    __shared__ int lcur[NBUCK];
    __shared__ int gbase[NBUCK];
    __shared__ int sbuf[256];
    __shared__ unsigned sedge[SCAT_TILE];
    __shared__ unsigned char sbuck[SCAT_TILE];
    __shared__ float sW[F_IN*HD];
    __shared__ float sb[HD];
    int t = threadIdx.x;

    if (blockIdx.x >= nsb){
        int bid2 = blockIdx.x - nsb;
        if (bid2 < PREPW_BLKS){                            // WT transpose
            int i = bid2*256 + t;
            int l = i >> 14;
            int r = (i >> 7) & 127;
            int c = i & 127;
            WT[(l << 14) + c*HD + r] = f2bf(Wc[i]);
            return;
        }
        int bid = bid2 - PREPW_BLKS;                       // proj
        for (int q = t; q < F_IN*HD; q += 256) sW[q] = Wp[q];
        if (t < HD) sb[t] = bp[t];
        __syncthreads();
        int j  = t & 63;
        int ln = t >> 6;
        for (int n0 = bid*4 + ln; n0 < n; n0 += PROJ_BLKS*4){
            float a0 = sb[2*j], a1 = sb[2*j+1];
            #pragma unroll
            for (int k = 0; k < F_IN; k++){
                float xv = x[(size_t)n0*F_IN + k];
                a0 += xv * sW[k*HD + 2*j];
                a1 += xv * sW[k*HD + 2*j+1];
            }
            hbf[(size_t)n0*64 + j] = packbf(fmaxf(a0, 0.f), fmaxf(a1, 0.f));
        }
        return;
    }

    // ---- edge scatter range ----
    int i0 = blockIdx.x*SCAT_TILE + t;
    int r[16], c[16];
    if (t < NBUCK) lcur[t] = 0;
    __syncthreads();
    #pragma unroll
    for (int k = 0; k < 16; k++){
        int i = i0 + k*256;
        if (i < e){
            r[k] = rows[i]; c[k] = cols[i];
            atomicAdd(&lcur[r[k] >> 9], 1);
        } else r[k] = -1;
    }
    __syncthreads();
    int myc = (t < NBUCK) ? lcur[t] : 0;
    sbuf[t] = myc;
    __syncthreads();
    for (int d = 1; d < 256; d <<= 1){
        int tv = (t >= d) ? sbuf[t-d] : 0;
        __syncthreads();
        sbuf[t] += tv;
        __syncthreads();
    }
    if (t < NBUCK){
        lbase[t] = sbuf[t] - myc;
        lcur[t]  = sbuf[t] - myc;
        if (myc > 0) gbase[t] = t*BCAP + atomicAdd(&gcur[t], myc);
    }
    __syncthreads();
    #pragma unroll
    for (int k = 0; k < 16; k++){
        if (r[k] >= 0){
            int bk = r[k] >> 9;
            int off = atomicAdd(&lcur[bk], 1);
            sedge[off] = ((unsigned)(r[k] & 511) << 17) | (unsigned)c[k];
            sbuck[off] = (unsigned char)bk;
        }
    }
    __syncthreads();
    int tot = sbuf[255];
    for (int i = t; i < tot; i += 256){
        int bk = sbuck[i];
        ebuf[gbase[bk] + (i - lbase[bk])] = sedge[i];
    }
}

// ---------------- k_build (R13 exact) ----------------
__global__ __launch_bounds__(512) void k_build(const unsigned* __restrict__ ebuf,
        const int* __restrict__ gcur, int* __restrict__ rowptr,
        float* __restrict__ dinv, int* __restrict__ colidx, int n, int etot){
    __shared__ int hist[512];
    __shared__ int cur[512];
    __shared__ int colstage[BUCK_CAP];
    __shared__ int sscan[256];
    int t = threadIdx.x;
    int gval = (t < NBUCK) ? gcur[t] : 0;
    if (t < 256) sscan[t] = gval;
    __syncthreads();
    for (int d = 1; d < 256; d <<= 1){
        int tv = (t < 256 && t >= d) ? sscan[t-d] : 0;
        __syncthreads();
        if (t < 256) sscan[t] += tv;
        __syncthreads();
    }
    int b = blockIdx.x;
    int cnt = gcur[b];
    int s   = sscan[b] - cnt;          // dense base in colidx
    int sp  = b*BCAP;                  // padded base in ebuf
    int row0 = b << 9;
    int nrows = min(512, n - row0);
    if (b == 0 && t == 0) rowptr[n] = etot;
    hist[t] = 0;
    __syncthreads();
    for (int i = t; i < cnt; i += 512)
        atomicAdd(&hist[ebuf[sp + i] >> 17], 1);
    __syncthreads();
    int myc = hist[t];
    cur[t] = myc;
    __syncthreads();
    for (int d = 1; d < 512; d <<= 1){
        int tv = (t >= d) ? cur[t-d] : 0;
        __syncthreads();
        cur[t] += tv;
        __syncthreads();
    }
    int excl = cur[t] - myc;
    if (t < nrows){
        rowptr[row0 + t] = s + excl;
        dinv[row0 + t] = rsqrtf((float)(myc + 1));   // +1 self loop
    }
    cur[t] = excl;
    __syncthreads();
    for (int i = t; i < cnt; i += 512){
        unsigned v = ebuf[sp + i];
        int off = atomicAdd(&cur[v >> 17], 1);
        colstage[off] = (int)(v & 0x1ffffu);
    }
    __syncthreads();
    for (int i = t; i < cnt; i += 512)
        colidx[s + i] = colstage[i];
}

// ---------------- layer GEMM (bf16 MFMA): 512 threads, 128-row tile (R14 exact) ----------------
__global__ __launch_bounds__(512) void k_gemm(const unsigned short* __restrict__ hbf,
        const unsigned short* __restrict__ WT, const float* __restrict__ dinv,
        unsigned short* __restrict__ hw, int n){
    extern __shared__ char smem[];
    unsigned short* As = (unsigned short*)smem;            // 128 x LDS_PITCH
    unsigned short* Bs = As + 128*LDS_PITCH;               // 128 x LDS_PITCH
    int tid = threadIdx.x;
    int row0 = blockIdx.x * 128;

    const uint4* h4 = (const uint4*)hbf;
    const uint4* w4 = (const uint4*)WT;
    #pragma unroll
    for (int q = tid; q < 2048; q += 512){                 // 128 rows x 16 chunks of 16B
        int r = q >> 4, c = q & 15;
        uint4 v = make_uint4(0u,0u,0u,0u);
        if (row0 + r < n) v = h4[(size_t)(row0 + r)*16 + c];
        *(uint4*)&As[r*LDS_PITCH + c*8] = v;
        *(uint4*)&Bs[r*LDS_PITCH + c*8] = w4[r*16 + c];
    }
    __syncthreads();

    int w = tid >> 6, lane = tid & 63;                     // 8 waves
    int l15 = lane & 15, quad = lane >> 4;
    f32x4 acc[8];
    #pragma unroll
    for (int ct = 0; ct < 8; ct++) acc[ct] = (f32x4){0.f,0.f,0.f,0.f};

    int arow = w*16 + l15;
    #pragma unroll
    for (int kc = 0; kc < 4; kc++){
        int ko = kc*32 + quad*8;
        bf8 a = *(const bf8*)&As[arow*LDS_PITCH + ko];
        #pragma unroll
        for (int ct = 0; ct < 8; ct++){
            bf8 b = *(const bf8*)&Bs[(ct*16 + l15)*LDS_PITCH + ko];
            acc[ct] = __builtin_amdgcn_mfma_f32_16x16x32_bf16(a, b, acc[ct], 0, 0, 0);
        }
    }
    __syncthreads();                                       // done reading As/Bs

    unsigned short* CS = As;
    #pragma unroll
    for (int reg = 0; reg < 4; reg++){
        int rloc = w*16 + quad*4 + reg;
        int grow = row0 + rloc;
        float dv = (grow < n) ? dinv[grow] : 0.f;
        #pragma unroll
        for (int ct = 0; ct < 8; ct++)
            CS[rloc*CPITCH + ct*16 + l15] = f2bf(acc[ct][reg] * dv);
    }
    __syncthreads();

    #pragma unroll
    for (int q = tid; q < 2048; q += 512){                 // coalesced uint4 store-out
        int r = q >> 4, c = q & 15;
        if (row0 + r < n)
            *(uint4*)&hw[(size_t)(row0 + r)*HD + c*8] = *(const uint4*)&CS[r*CPITCH + c*8];
    }
}

// ---------------- aggregation + bias + BN + relu ----------------
// R19: revert to R1's proven shape (4 nodes/wave, 16 lanes x uint4 gathers,
// 64 us), plus two latency fixes inside the same structure:
//  (1) predicated 8-wide tail: the deg%8 remainder (mean 3.5 edges) used to
//      run 1-edge-per-round-trip serially (~25% of loop time); now all
//      remaining gathers issue together under exec-mask (masked lanes send
//      no requests -> no extra traffic), one round-trip total.
//  (2) colidx software pipeline: next iteration's 8 indices load while the
//      current 8 gathers are in flight, taking the ~200cy L2 colidx latency
//      off the critical path.
// Accumulation keeps the a/b dual chain; tail reorder is fp32-only (absmax
// has been bit-stable at 2^-11 bf16 quantization across all prior reorders).
__global__ __launch_bounds__(256) void k_agg(const uint4* __restrict__ hw4,
        const int* __restrict__ rowptr, const int* __restrict__ colidx,
        const float* __restrict__ dinv, const float* __restrict__ bc,
        const float* __restrict__ bmean, const float* __restrict__ bvar,
        const float* __restrict__ bgamma, const float* __restrict__ bbeta,
        uint4* __restrict__ houtb, int n){
    int lane = threadIdx.x & 63;
    int grp  = lane >> 4;                  // node-group within wave (0..3)
    int fl   = lane & 15;                  // feature-lane: covers feats [fl*8, fl*8+8)
    int node = blockIdx.x*16 + (threadIdx.x >> 6)*4 + grp;
    bool valid = node < n;
    int nd = valid ? node : 0;

    float a[8], b[8];
    uint4 self = hw4[(size_t)nd*16 + fl];
    a[0] = bflo(self.x); a[1] = bfhi(self.x);
    a[2] = bflo(self.y); a[3] = bfhi(self.y);
    a[4] = bflo(self.z); a[5] = bfhi(self.z);
    a[6] = bflo(self.w); a[7] = bfhi(self.w);
    #pragma unroll
    for (int j = 0; j < 8; j++) b[j] = 0.f;

    int s = rowptr[nd];
    int e = valid ? rowptr[nd+1] : s;
    int t = s;

    #define ACC(dst, v) { dst[0]+=bflo(v.x); dst[1]+=bfhi(v.x); \
                          dst[2]+=bflo(v.y); dst[3]+=bfhi(v.y); \
                          dst[4]+=bflo(v.z); dst[5]+=bfhi(v.z); \
                          dst[6]+=bflo(v.w); dst[7]+=bfhi(v.w); }

    int c0=0,c1=0,c2=0,c3=0,c4=0,c5=0,c6=0,c7=0;
    if (t + 8 <= e){
        c0 = colidx[t];   c1 = colidx[t+1];
        c2 = colidx[t+2]; c3 = colidx[t+3];
        c4 = colidx[t+4]; c5 = colidx[t+5];
        c6 = colidx[t+6]; c7 = colidx[t+7];
    }
    while (t + 8 <= e){
        uint4 v0 = hw4[(size_t)c0*16 + fl];
        uint4 v1 = hw4[(size_t)c1*16 + fl];
        uint4 v2 = hw4[(size_t)c2*16 + fl];
        uint4 v3 = hw4[(size_t)c3*16 + fl];
        uint4 v4 = hw4[(size_t)c4*16 + fl];
        uint4 v5 = hw4[(size_t)c5*16 + fl];
        uint4 v6 = hw4[(size_t)c6*16 + fl];
        uint4 v7 = hw4[(size_t)c7*16 + fl];
        int tn = t + 8;
        if (tn + 8 <= e){                                  // prefetch next indices
            c0 = colidx[tn];   c1 = colidx[tn+1];
            c2 = colidx[tn+2]; c3 = colidx[tn+3];
            c4 = colidx[tn+4]; c5 = colidx[tn+5];
            c6 = colidx[tn+6]; c7 = colidx[tn+7];
        }
        ACC(a, v0); ACC(b, v1); ACC(a, v2); ACC(b, v3);
        ACC(a, v4); ACC(b, v5); ACC(a, v6); ACC(b, v7);
        t = tn;
    }

    // predicated tail: 0..7 edges, all gathers issued together (one round-trip)
    int rem = e - t;
    uint4 w0, w1, w2, w3, w4, w5, w6, w7;
    if (rem > 0) w0 = hw4[(size_t)colidx[t]*16 + fl];
    if (rem > 1) w1 = hw4[(size_t)colidx[t+1]*16 + fl];
    if (rem > 2) w2 = hw4[(size_t)colidx[t+2]*16 + fl];
    if (rem > 3) w3 = hw4[(size_t)colidx[t+3]*16 + fl];
    if (rem > 4) w4 = hw4[(size_t)colidx[t+4]*16 + fl];
    if (rem > 5) w5 = hw4[(size_t)colidx[t+5]*16 + fl];
    if (rem > 6) w6 = hw4[(size_t)colidx[t+6]*16 + fl];
    if (rem > 0) ACC(a, w0);
    if (rem > 1) ACC(b, w1);
    if (rem > 2) ACC(a, w2);
    if (rem > 3) ACC(b, w3);
    if (rem > 4) ACC(a, w4);
    if (rem > 5) ACC(b, w5);
    if (rem > 6) ACC(a, w6);
    (void)w7;
    #undef ACC
    #pragma unroll
    for (int j = 0; j < 8; j++) a[j] += b[j];

    if (!valid) return;
    float dv = dinv[node];
    const float4* B4 = (const float4*)bc;
    const float4* M4 = (const float4*)bmean;
    const float4* V4 = (const float4*)bvar;
    const float4* G4 = (const float4*)bgamma;
    const float4* T4 = (const float4*)bbeta;
    float4 cb[2] = {B4[fl*2], B4[fl*2+1]};
    float4 cm[2] = {M4[fl*2], M4[fl*2+1]};
    float4 cv[2] = {V4[fl*2], V4[fl*2+1]};
    float4 cg[2] = {G4[fl*2], G4[fl*2+1]};
    float4 ct[2] = {T4[fl*2], T4[fl*2+1]};
    float r[8];
    #pragma unroll
    for (int j = 0; j < 8; j++){
        float cbj = ((const float*)cb)[j];
        float cmj = ((const float*)cm)[j];
        float cvj = ((const float*)cv)[j];
        float cgj = ((const float*)cg)[j];
        float ctj = ((const float*)ct)[j];
        float rx = (a[j]*dv + cbj - cmj) * rsqrtf(cvj + BN_EPS) * cgj + ctj;
        r[j] = fmaxf(rx, 0.f);
    }
    uint4 o;
    o.x = packbf(r[0], r[1]);
    o.y = packbf(r[2], r[3]);
    o.z = packbf(r[4], r[5]);
    o.w = packbf(r[6], r[7]);
    houtb[(size_t)node*16 + fl] = o;
}

// ---------------- pooling on bf16 h (fp32 accumulate, R9 exact) ----------------
__global__ void k_pool(const unsigned* __restrict__ hb, const int* __restrict__ batch,
        float* __restrict__ gsum, int* __restrict__ gmax, int n){
    int q = threadIdx.x;   // 0..63 feature pair
    int start = blockIdx.x * POOL_TILE;
    int end = min(start + POOL_TILE, n);
    if (start >= end) return;
    int cur = batch[start];
    float s0 = 0.f, s1 = 0.f, m0 = 0.f, m1 = 0.f;
    for (int i = start; i < end; i++){
        int b = batch[i];
        unsigned v = hb[(size_t)i*64 + q];
        float v0 = bflo(v), v1 = bfhi(v);
        if (b != cur){
            atomicAdd(&gsum[cur*HD + 2*q],     s0);
            atomicAdd(&gsum[cur*HD + 2*q + 1], s1);
            atomicMax(&gmax[cur*HD + 2*q],     __float_as_int(m0));
            atomicMax(&gmax[cur*HD + 2*q + 1], __float_as_int(m1));
            s0 = s1 = m0 = m1 = 0.f; cur = b;
        }
        s0 += v0; s1 += v1;
        m0 = fmaxf(m0, v0); m1 = fmaxf(m1, v1);
    }
    atomicAdd(&gsum[cur*HD + 2*q],     s0);
    atomicAdd(&gsum[cur*HD + 2*q + 1], s1);
    atomicMax(&gmax[cur*HD + 2*q],     __float_as_int(m0));
    atomicMax(&gmax[cur*HD + 2*q + 1], __float_as_int(m1));
}

// ---------------- fused head: count (binary search) + MLP1 + MLP2 ----------------
__global__ void k_head(const float* __restrict__ gsum, const int* __restrict__ gmax,
        const int* __restrict__ batch, const float* __restrict__ W1,
        const float* __restrict__ b1, const float* __restrict__ W2,
        const float* __restrict__ b2, float* __restrict__ out, int n){
    __shared__ float gv[2*HD];
    __shared__ float hid[HD];
    __shared__ int bound[2];
    int g = blockIdx.x, j = threadIdx.x;   // 128 threads
    if (j < 2){
        int target = g + j;
        int lo = 0, hi = n;
        while (lo < hi){ int mid = (lo + hi) >> 1; if (batch[mid] < target) lo = mid + 1; else hi = mid; }
        bound[j] = lo;
    }
    __syncthreads();
    float denom = (float)max(bound[1] - bound[0], 1);
    gv[j]    = gsum[g*HD+j] / denom;
    gv[HD+j] = __int_as_float(gmax[g*HD+j]);   // 0 for empty graphs (matches guard)
    __syncthreads();
    float acc = b1[j];
    #pragma unroll 8
    for (int k = 0; k < 2*HD; k++) acc += gv[k]*W1[k*HD + j];
    hid[j] = fmaxf(acc, 0.f);
    __syncthreads();
    if (j < N_CLASSES){
        float o = b2[j];
        #pragma unroll 4
        for (int k = 0; k < HD; k++) o += hid[k]*W2[k*N_CLASSES + j];
        out[g*N_CLASSES + j] = o;
    }
}

// ---------------- launch ----------------
extern "C" void kernel_launch(void* const* d_in, const int* in_sizes, int n_in,
                              void* d_out, int out_size, void* d_ws, size_t ws_size,
                              hipStream_t stream){
    const float* x   = (const float*)d_in[0];
    const int*  eidx = (const int*)d_in[1];
    const int* batch = (const int*)d_in[2];
    const float* Wp  = (const float*)d_in[3];
    const float* bp  = (const float*)d_in[4];
    const float* Wc  = (const float*)d_in[5];
    const float* bc  = (const float*)d_in[6];
    const float* bng = (const float*)d_in[7];
    const float* bnb = (const float*)d_in[8];
    const float* bnm = (const float*)d_in[9];
    const float* bnv = (const float*)d_in[10];
    const float* W1  = (const float*)d_in[11];
    const float* b1  = (const float*)d_in[12];
    const float* W2  = (const float*)d_in[13];
    const float* b2  = (const float*)d_in[14];
    float* out = (float*)d_out;

    // workspace (~68 MB). gcur|gsum|gmax contiguous -> one memset.
    char* ws = (char*)d_ws;
    size_t off = 0;
    unsigned short* h_bf  = (unsigned short*)(ws + off); off += (size_t)N_NODES*HD*2;  // 25.6 MB
    unsigned short* hw_bf = (unsigned short*)(ws + off); off += (size_t)N_NODES*HD*2;  // 25.6 MB
    unsigned short* WT = (unsigned short*)(ws + off); off += (size_t)N_LAYERS*HD*HD*2; // 98 KB
    float* dinv   = (float*)(ws + off); off += (size_t)N_NODES*4;
    int*   rowptr = (int*)  (ws + off); off += (size_t)(N_NODES+16)*4;
    int*   colidx = (int*)  (ws + off); off += (size_t)N_EDGES*4;                      // 6.4 MB
    unsigned* ebuf= (unsigned*)(ws + off); off += (size_t)NBUCK*BCAP*4;                // 7.2 MB padded
    int*   gcur   = (int*)  (ws + off); off += 1024;                                   // zeroed region start
    float* gsum   = (float*)(ws + off); off += (size_t)N_GRAPHS*HD*4;
    int*   gmax   = (int*)  (ws + off); off += (size_t)N_GRAPHS*HD*4;

    const int* rows = eidx;             // targets (aggregation index)
    const int* cols = eidx + N_EDGES;   // sources (gather index)

    // single memset: gcur + gsum + gmax (contiguous)
    hipMemsetAsync(gcur, 0, 1024 + (size_t)(N_GRAPHS*HD*2)*4, stream);

    int nsb = (N_EDGES + SCAT_TILE - 1)/SCAT_TILE;   // 391
    k_scatter<<<nsb + PREPW_BLKS + PROJ_BLKS, 256, 0, stream>>>(rows, cols, gcur, ebuf,
        N_EDGES, nsb, Wc, WT, x, Wp, bp, (unsigned*)h_bf, N_NODES);
    k_build  <<<NBUCK, 512, 0, stream>>>(ebuf, gcur, rowptr, dinv, colidx, N_NODES, N_EDGES);

    int ntiles = (N_NODES + 127)/128;   // 782
    size_t shmem = (size_t)(2*128*LDS_PITCH)*2;   // 77,824 B -> 2 blocks/CU, 16 waves/CU
    for (int l = 0; l < N_LAYERS; l++){
        k_gemm<<<ntiles, 512, shmem, stream>>>(h_bf, WT + (size_t)l*HD*HD, dinv, hw_bf, N_NODES);
        k_agg<<<(N_NODES+15)/16, 256, 0, stream>>>((const uint4*)hw_bf, rowptr, colidx, dinv,
            bc + l*HD, bnm + l*HD, bnv + l*HD, bng + l*HD, bnb + l*HD,
            (uint4*)h_bf, N_NODES);
    }

    k_pool<<<(N_NODES+POOL_TILE-1)/POOL_TILE, 64, 0, stream>>>((const unsigned*)h_bf, batch, gsum, gmax, N_NODES);
    k_head<<<N_GRAPHS, 128, 0, stream>>>(gsum, gmax, batch, W1, b1, W2, b2, out, N_NODES);
}